// Round 10
// baseline (581.831 us; speedup 1.0000x reference)
//
#include <hip/hip_runtime.h>
#include <hip/hip_bf16.h>

// TransformerBlock fused kernel for MI355X (gfx950) — v9: register-resident
// pipeline; LDS only for K/Vt; ONE barrier.
// Shapes: B=1024, T=128, D=128, H=4, HD=32, FF=512.
// One block per batch element; 512 threads = 8 waves. LDS 69,632 B.
//
// Insight: only K and Vt are cross-wave data. Everything else (hs, Q, attn,
// x1, h2, G, ff) is per-wave per-16-token -> kept in registers as MFMA frags:
//  - Each wave owns tokens trow = w*16+lq and iterates WEIGHT tiles (bf16,
//    pre-converted in d_ws; Wq pre-scaled by SCALE*log2e) against fixed
//    activation B-frags. C-layout -> next B-frags via quad_collect_pk
//    (verified v3/v4/v7/v8).
//  - P1 (after in-reg LN1, v7-verified): K -> LDS b64 rows; Q -> reg frags;
//    Vt -> LDS b16 scatter. ONE __syncthreads().
//  - P2 (v8-verified softmax/PV): attn accumulates in packed registers.
//  - P3..P6: Wo-GEMM, LN2 (cross-quad reduce), W1->relu->W2, +b2, store —
//    all registers, zero LDS, zero barriers.
// MFMA totals unchanged (448/wave). Occupancy stays 8 waves/CU (unified
// VGPR+AGPR wall, proven v2.1-v7); this attacks per-wave critical path.
// MFMA 16x16x32 bf16. A-frag: A[m=lane&15][k=quad*8+j]; B-frag:
// B[k=quad*8+j][n=lane&15]; C/D: col=lane&15 (n), row=quad*4+reg (m).

typedef short bf16x8 __attribute__((ext_vector_type(8)));   // 8 bf16 in 4 VGPRs
typedef float f32x4  __attribute__((ext_vector_type(4)));
typedef unsigned short u16;
typedef unsigned int   u32;

#define TT   128
#define DDIM 128
#define FFD  512
#define PIT  136   // LDS row pitch (bf16): 272 B -> rows 16B-aligned

// ws layout (u16 element offsets) for bf16 weight copies
#define OWQ 0
#define OWK 16384
#define OWV 32768
#define OWO 49152
#define OW1 65536
#define OW2 131072
#define WTOT 196608

// SCALE * log2(e), folded into Wq at prep time. SCALE = 128^-0.5.
#define QSC 0.12751744f

#if defined(__has_builtin)
#if __has_builtin(__builtin_amdgcn_exp2f)
#define EXP2F(x) __builtin_amdgcn_exp2f(x)
#else
#define EXP2F(x) exp2f(x)
#endif
#else
#define EXP2F(x) exp2f(x)
#endif

__device__ __forceinline__ u16 f2b(float f) {
    __hip_bfloat16 h = __float2bfloat16(f);   // RNE
    return __builtin_bit_cast(u16, h);
}
__device__ __forceinline__ u32 pk2(float x, float y) {
    return (u32)f2b(x) | ((u32)f2b(y) << 16);
}
__device__ __forceinline__ void st_b64(u16* p, u32 lo, u32 hi) {  // 8B-aligned
    uint2 v; v.x = lo; v.y = hi;
    *reinterpret_cast<uint2*>(p) = v;
}
__device__ __forceinline__ bf16x8 ldfrag(const u16* p) {  // LDS/global, 16B-aligned
    return __builtin_bit_cast(bf16x8, *reinterpret_cast<const uint4*>(p));
}
__device__ __forceinline__ f32x4 mfma16(bf16x8 a, bf16x8 b, f32x4 c) {
    return __builtin_amdgcn_mfma_f32_16x16x32_bf16(a, b, c, 0, 0, 0);
}

// Cross-quad repack (verified v3/v4/v7/v8): pkv[i][d0] =
// pack(V[row][i*16+quad*4+2*d0], V[row][i*16+quad*4+2*d0+1]) — C-layout
// columns of this lane's row; output fr[g][j] = bf16(V[row][g*32+quad*8+j])
// (A/B-frag layout). Row (= lane&15 group) preserved; only quad-dim moves.
__device__ __forceinline__ void quad_collect_pk(const u32 (&pkv)[8][2],
                                                bf16x8 (&fr)[4], int lane) {
    const int srcA = (lane & 15) + ((lane & 16) << 1);  // lq + 32*l4'
    const int srcB = srcA + 16;
    const bool hi = (lane & 32) != 0;                   // l5'
    #pragma unroll
    for (int g = 0; g < 4; g++) {
        u32 D00 = pkv[2*g][0],     D01 = pkv[2*g][1];
        u32 D10 = pkv[2*g + 1][0], D11 = pkv[2*g + 1][1];
        u32 a00 = (u32)__shfl((int)D00, srcA);
        u32 a10 = (u32)__shfl((int)D10, srcA);
        u32 a01 = (u32)__shfl((int)D01, srcA);
        u32 a11 = (u32)__shfl((int)D11, srcA);
        u32 b00 = (u32)__shfl((int)D00, srcB);
        u32 b10 = (u32)__shfl((int)D10, srcB);
        u32 b01 = (u32)__shfl((int)D01, srcB);
        u32 b11 = (u32)__shfl((int)D11, srcB);
        uint4 q;
        q.x = hi ? a10 : a00;
        q.y = hi ? a11 : a01;
        q.z = hi ? b10 : b00;
        q.w = hi ? b11 : b01;
        fr[g] = __builtin_bit_cast(bf16x8, q);
    }
}

// Weight prep: f32 -> bf16 copies into workspace (one tiny dispatch, ~3 us).
// Wq additionally scaled by QSC (folds softmax scale + log2e into Q).
__global__ __launch_bounds__(256) void wprep(
    const float* __restrict__ wq, const float* __restrict__ wk,
    const float* __restrict__ wv, const float* __restrict__ wo,
    const float* __restrict__ w1, const float* __restrict__ w2,
    u16* __restrict__ dst)
{
    int i = (blockIdx.x * 256 + threadIdx.x) * 8;
    if (i >= WTOT) return;
    const float* s; int off; float sc = 1.0f;
    if      (i < OWK) { s = wq; off = i - OWQ; sc = QSC; }
    else if (i < OWV) { s = wk; off = i - OWK; }
    else if (i < OWO) { s = wv; off = i - OWV; }
    else if (i < OW1) { s = wo; off = i - OWO; }
    else if (i < OW2) { s = w1; off = i - OW1; }
    else              { s = w2; off = i - OW2; }
    float4 a = *reinterpret_cast<const float4*>(s + off);
    float4 b = *reinterpret_cast<const float4*>(s + off + 4);
    uint4 o;
    o.x = pk2(a.x * sc, a.y * sc); o.y = pk2(a.z * sc, a.w * sc);
    o.z = pk2(b.x * sc, b.y * sc); o.w = pk2(b.z * sc, b.w * sc);
    *reinterpret_cast<uint4*>(dst + i) = o;
}

__global__ __launch_bounds__(512, 2) void tblock_kernel(
    const float* __restrict__ x,
    const float* __restrict__ ln1g, const float* __restrict__ ln1b,
    const u16*  __restrict__ wbf,
    const float* __restrict__ bo,
    const float* __restrict__ ln2g, const float* __restrict__ ln2b,
    const float* __restrict__ b1,   const float* __restrict__ b2,
    float* __restrict__ out)
{
    // 69,632 B: bufK = K[t][dk] (b64 rows); bufV = Vt[o][t] (b16 scatter).
    __shared__ __align__(16) u16 sm[2 * TT * PIT];
    u16* bufK = sm;
    u16* bufV = sm + TT * PIT;

    const int b    = blockIdx.x;
    const int tid  = threadIdx.x;
    const int w    = tid >> 6;     // wave id 0..7
    const int l    = tid & 63;
    const int lq   = l & 15;
    const int quad = l >> 4;
    const int trow = w * 16 + lq;  // this lane's token row (wave-owned tile)
    const float* xb = x + (size_t)b * (TT * DDIM);

    const u16* wq = wbf + OWQ;
    const u16* wk = wbf + OWK;
    const u16* wv = wbf + OWV;
    const u16* wo = wbf + OWO;
    const u16* w1 = wbf + OW1;
    const u16* w2 = wbf + OW2;

    // ---------------- LN1 in registers (own row) -> hf[4] B-frags ----------
    // (v7-verified) hf[ks][j] = hs[trow][ks*32+quad*8+j]
    bf16x8 hf[4];
    {
        float v[32];
        float s = 0.f, s2 = 0.f;
        #pragma unroll
        for (int ks = 0; ks < 4; ks++) {
            const float* src = xb + trow * DDIM + ks * 32 + quad * 8;
            float4 u0 = *reinterpret_cast<const float4*>(src);
            float4 u1 = *reinterpret_cast<const float4*>(src + 4);
            v[ks*8+0]=u0.x; v[ks*8+1]=u0.y; v[ks*8+2]=u0.z; v[ks*8+3]=u0.w;
            v[ks*8+4]=u1.x; v[ks*8+5]=u1.y; v[ks*8+6]=u1.z; v[ks*8+7]=u1.w;
            s  += u0.x+u0.y+u0.z+u0.w + u1.x+u1.y+u1.z+u1.w;
            s2 += u0.x*u0.x+u0.y*u0.y+u0.z*u0.z+u0.w*u0.w
                + u1.x*u1.x+u1.y*u1.y+u1.z*u1.z+u1.w*u1.w;
        }
        s  += __shfl_xor(s, 16);  s2 += __shfl_xor(s2, 16);
        s  += __shfl_xor(s, 32);  s2 += __shfl_xor(s2, 32);
        float mean = s * (1.f / 128.f);
        float var  = fmaxf(s2 * (1.f / 128.f) - mean * mean, 0.f);
        float rstd = rsqrtf(var + 1e-5f);
        #pragma unroll
        for (int ks = 0; ks < 4; ks++) {
            const float* gp = ln1g + ks * 32 + quad * 8;
            const float* bp = ln1b + ks * 32 + quad * 8;
            float4 g0 = *reinterpret_cast<const float4*>(gp);
            float4 g1 = *reinterpret_cast<const float4*>(gp + 4);
            float4 c0 = *reinterpret_cast<const float4*>(bp);
            float4 c1 = *reinterpret_cast<const float4*>(bp + 4);
            float gg[8] = {g0.x,g0.y,g0.z,g0.w,g1.x,g1.y,g1.z,g1.w};
            float bb[8] = {c0.x,c0.y,c0.z,c0.w,c1.x,c1.y,c1.z,c1.w};
            #pragma unroll
            for (int j = 0; j < 8; j++)
                hf[ks][j] = (short)f2b((v[ks*8+j] - mean) * rstd * gg[j] + bb[j]);
        }
    }

    // ---------------- P1: K -> bufK (b64), Q -> reg frags, Vt -> bufV ------
    #pragma unroll
    for (int mt = 0; mt < 8; mt++) {
        f32x4 acc = {0, 0, 0, 0};
        #pragma unroll
        for (int ks = 0; ks < 4; ks++)
            acc = mfma16(ldfrag(wk + (mt * 16 + lq) * DDIM + ks * 32 + quad * 8), hf[ks], acc);
        st_b64(bufK + trow * PIT + mt * 16 + quad * 4,
               pk2(acc[0], acc[1]), pk2(acc[2], acc[3]));
    }
    bf16x8 qf[4];   // Q B-frags: qf[h][j] = Q[trow][h*32+quad*8+j] (pre-scaled)
    {
        u32 qpk[8][2];
        #pragma unroll
        for (int mt = 0; mt < 8; mt++) {
            f32x4 acc = {0, 0, 0, 0};
            #pragma unroll
            for (int ks = 0; ks < 4; ks++)
                acc = mfma16(ldfrag(wq + (mt * 16 + lq) * DDIM + ks * 32 + quad * 8), hf[ks], acc);
            qpk[mt][0] = pk2(acc[0], acc[1]);
            qpk[mt][1] = pk2(acc[2], acc[3]);
        }
        quad_collect_pk(qpk, qf, l);
    }
    #pragma unroll
    for (int mt = 0; mt < 8; mt++) {
        f32x4 acc = {0, 0, 0, 0};
        #pragma unroll
        for (int ks = 0; ks < 4; ks++)
            acc = mfma16(ldfrag(wv + (mt * 16 + lq) * DDIM + ks * 32 + quad * 8), hf[ks], acc);
        #pragma unroll
        for (int r = 0; r < 4; r++)
            bufV[(mt * 16 + quad * 4 + r) * PIT + trow] = f2b(acc[r]);
    }
    __syncthreads();   // the ONLY barrier: K/Vt complete

    // ---------------- P2: attention; attn accumulates in registers ---------
    u32 apk[8][2];   // packed attn row: apk[2h+half][d0] over d = h*32+half*16+quad*4+{2d0,2d0+1}
    #pragma unroll 1
    for (int h = 0; h < 4; h++) {
        // S^T = mfma(K-frag, Q-frag): p[n][r] = S[s=n*16+quad*4+r][t=trow]
        float p[8][4];
        #pragma unroll
        for (int n = 0; n < 8; n++) {
            bf16x8 ka = ldfrag(bufK + (n * 16 + lq) * PIT + h * 32 + quad * 8);
            f32x4 s4 = mfma16(ka, qf[h], f32x4{0, 0, 0, 0});
            #pragma unroll
            for (int r = 0; r < 4; r++) p[n][r] = s4[r];
        }
        // causal softmax (exp2 domain, scale pre-folded into Wq, norm deferred)
        float mx = -3.0e38f;
        #pragma unroll
        for (int n = 0; n < 8; n++) {
            #pragma unroll
            for (int r = 0; r < 4; r++) {
                int sc = n * 16 + quad * 4 + r;
                mx = (sc <= trow) ? fmaxf(mx, p[n][r]) : mx;
            }
        }
        mx = fmaxf(mx, __shfl_xor(mx, 16));
        mx = fmaxf(mx, __shfl_xor(mx, 32));   // full-row max
        float sum = 0.f;
        u32 ppk[8][2];   // unnormalized exp, packed bf16 pairs
        #pragma unroll
        for (int n = 0; n < 8; n++) {
            int sc = n * 16 + quad * 4;
            float e0 = (sc     <= trow) ? EXP2F(p[n][0] - mx) : 0.f;
            float e1 = (sc + 1 <= trow) ? EXP2F(p[n][1] - mx) : 0.f;
            float e2 = (sc + 2 <= trow) ? EXP2F(p[n][2] - mx) : 0.f;
            float e3 = (sc + 3 <= trow) ? EXP2F(p[n][3] - mx) : 0.f;
            sum += e0 + e1 + e2 + e3;
            ppk[n][0] = pk2(e0, e1);
            ppk[n][1] = pk2(e2, e3);
        }
        sum += __shfl_xor(sum, 16);
        sum += __shfl_xor(sum, 32);           // full-row sum
        float inv = 1.f / sum;   // sum >= 1 (max entry contributes exp2(0)=1)
        // P -> B-frags in-register; swapped PV: C[o][t=trow]
        bf16x8 pfr[4];
        quad_collect_pk(ppk, pfr, l);
        f32x4 o0 = {0, 0, 0, 0}, o1 = {0, 0, 0, 0};
        #pragma unroll
        for (int ks = 0; ks < 4; ks++) {
            bf16x8 va0 = ldfrag(bufV + (h * 32 + lq) * PIT + ks * 32 + quad * 8);
            bf16x8 va1 = ldfrag(bufV + (h * 32 + 16 + lq) * PIT + ks * 32 + quad * 8);
            o0 = mfma16(va0, pfr[ks], o0);
            o1 = mfma16(va1, pfr[ks], o1);
        }
        apk[2 * h + 0][0] = pk2(o0[0] * inv, o0[1] * inv);
        apk[2 * h + 0][1] = pk2(o0[2] * inv, o0[3] * inv);
        apk[2 * h + 1][0] = pk2(o1[0] * inv, o1[1] * inv);
        apk[2 * h + 1][1] = pk2(o1[2] * inv, o1[3] * inv);
    }

    // ---------------- P3: oacc = x1 = x + attn @ Wo^T + bo (registers) -----
    f32x4 oacc[8];   // [d = mt*16+quad*4+r][t = trow]
    {
        bf16x8 af[4];
        quad_collect_pk(apk, af, l);   // attn B-frags: B[k=d_in][n=t]
        #pragma unroll
        for (int mt = 0; mt < 8; mt++) {
            f32x4 acc = {0, 0, 0, 0};
            #pragma unroll
            for (int ks = 0; ks < 4; ks++)
                acc = mfma16(ldfrag(wo + (mt * 16 + lq) * DDIM + ks * 32 + quad * 8), af[ks], acc);
            const float4 xv  = *reinterpret_cast<const float4*>(xb + trow * DDIM + mt * 16 + quad * 4);
            const float4 bo4 = *reinterpret_cast<const float4*>(bo + mt * 16 + quad * 4);
            oacc[mt][0] = acc[0] + xv.x + bo4.x;
            oacc[mt][1] = acc[1] + xv.y + bo4.y;
            oacc[mt][2] = acc[2] + xv.z + bo4.z;
            oacc[mt][3] = acc[3] + xv.w + bo4.w;
        }
    }

    // ---------------- P4: LN2 in registers -> h2f[4] B-frags ---------------
    bf16x8 h2f[4];
    {
        float s = 0.f, s2 = 0.f;
        #pragma unroll
        for (int mt = 0; mt < 8; mt++) {
            #pragma unroll
            for (int r = 0; r < 4; r++) {
                float v = oacc[mt][r];
                s += v; s2 += v * v;
            }
        }
        s  += __shfl_xor(s, 16);  s2 += __shfl_xor(s2, 16);
        s  += __shfl_xor(s, 32);  s2 += __shfl_xor(s2, 32);
        float mean = s * (1.f / 128.f);
        float var  = fmaxf(s2 * (1.f / 128.f) - mean * mean, 0.f);
        float rstd = rsqrtf(var + 1e-5f);
        u32 hpk[8][2];
        #pragma unroll
        for (int mt = 0; mt < 8; mt++) {
            const float4 g4 = *reinterpret_cast<const float4*>(ln2g + mt * 16 + quad * 4);
            const float4 c4 = *reinterpret_cast<const float4*>(ln2b + mt * 16 + quad * 4);
            float h0 = (oacc[mt][0] - mean) * rstd * g4.x + c4.x;
            float h1 = (oacc[mt][1] - mean) * rstd * g4.y + c4.y;
            float h2 = (oacc[mt][2] - mean) * rstd * g4.z + c4.z;
            float h3 = (oacc[mt][3] - mean) * rstd * g4.w + c4.w;
            hpk[mt][0] = pk2(h0, h1);
            hpk[mt][1] = pk2(h2, h3);
        }
        quad_collect_pk(hpk, h2f, l);   // B[k=d][n=t]
    }

    // ---------------- P5: FF entirely in registers; oacc += ff -------------
    #pragma unroll 1
    for (int fc = 0; fc < 4; fc++) {
        const int fbase = fc * 128;
        // G = relu(h2 @ W1c^T + b1): C[f = ft*16+quad*4+r][t = trow]
        u32 gpk[8][2];
        #pragma unroll
        for (int ft = 0; ft < 8; ft++) {
            f32x4 acc = {0, 0, 0, 0};
            #pragma unroll
            for (int ks = 0; ks < 4; ks++)
                acc = mfma16(ldfrag(w1 + (fbase + ft * 16 + lq) * DDIM + ks * 32 + quad * 8), h2f[ks], acc);
            const float4 b14 = *reinterpret_cast<const float4*>(b1 + fbase + ft * 16 + quad * 4);
            float g0 = fmaxf(acc[0] + b14.x, 0.f);
            float g1 = fmaxf(acc[1] + b14.y, 0.f);
            float g2 = fmaxf(acc[2] + b14.z, 0.f);
            float g3 = fmaxf(acc[3] + b14.w, 0.f);
            gpk[ft][0] = pk2(g0, g1);
            gpk[ft][1] = pk2(g2, g3);
        }
        bf16x8 gf[4];
        quad_collect_pk(gpk, gf, l);   // B[k=f(within fc)][n=t]
        // oacc += W2c @ G: C[d = dt*16+quad*4+r][t = trow]
        #pragma unroll
        for (int dt = 0; dt < 8; dt++) {
            #pragma unroll
            for (int ks = 0; ks < 4; ks++)
                oacc[dt] = mfma16(ldfrag(w2 + (dt * 16 + lq) * FFD + fbase + ks * 32 + quad * 8), gf[ks], oacc[dt]);
        }
    }

    // ---------------- P6: out = oacc + b2 (float4 stores, own rows) --------
    {
        float* ob = out + (size_t)b * (TT * DDIM);
        #pragma unroll
        for (int dt = 0; dt < 8; dt++) {
            const float4 b24 = *reinterpret_cast<const float4*>(b2 + dt * 16 + quad * 4);
            float4 o;
            o.x = oacc[dt][0] + b24.x;
            o.y = oacc[dt][1] + b24.y;
            o.z = oacc[dt][2] + b24.z;
            o.w = oacc[dt][3] + b24.w;
            *reinterpret_cast<float4*>(ob + trow * DDIM + dt * 16 + quad * 4) = o;
        }
    }
}

extern "C" void kernel_launch(void* const* d_in, const int* in_sizes, int n_in,
                              void* d_out, int out_size, void* d_ws, size_t ws_size,
                              hipStream_t stream) {
    const float* x    = (const float*)d_in[0];
    const float* ln1g = (const float*)d_in[1];
    const float* ln1b = (const float*)d_in[2];
    const float* Wq   = (const float*)d_in[3];
    const float* Wk   = (const float*)d_in[4];
    const float* Wv   = (const float*)d_in[5];
    const float* Wo   = (const float*)d_in[6];
    const float* bo   = (const float*)d_in[7];
    const float* ln2g = (const float*)d_in[8];
    const float* ln2b = (const float*)d_in[9];
    const float* W1   = (const float*)d_in[10];
    const float* b1   = (const float*)d_in[11];
    const float* W2   = (const float*)d_in[12];
    const float* b2   = (const float*)d_in[13];
    float* out = (float*)d_out;
    u16* wbf = (u16*)d_ws;   // needs WTOT*2 = 393,216 B (validated in v7/v8)

    wprep<<<dim3((WTOT / 8 + 255) / 256), dim3(256), 0, stream>>>(
        Wq, Wk, Wv, Wo, W1, W2, wbf);

    const int nblocks = in_sizes[0] / (TT * DDIM);   // B = 1024
    tblock_kernel<<<dim3(nblocks), dim3(512), 0, stream>>>(
        x, ln1g, ln1b, wbf, bo, ln2g, ln2b, b1, b2, out);
}